// Round 3
// baseline (886.279 us; speedup 1.0000x reference)
//
#include <hip/hip_runtime.h>
#include <math.h>

// Static feature buffer: 9216 images x 400 feats.
// [0, 1024)    : features of img[n]
// [1024, 9216) : features of train[refs[n*8+s]] at offset 1024 + n*8 + s
__device__ float g_feat[9216 * 400];

// ---------------------------------------------------------------------------
// Kernel 1: LeNet trunk, one block per image.
// LDS tiles XOR-swizzled on 16B slots by row&7 (conflict-free b128 reads).
// Work is spread across ALL FOUR waves (round-2 version put conv1 on waves
// 0-1 and conv2 on waves 0-2 only -> SIMD imbalance):
//   conv1: wave w handles och=w>>1, pos parity w&1; 49 lanes/wave, 196 items.
//          och is wave-uniform so weight reads stay scalar (s_load).
//   conv2: item w=(oc*10+oy) -> q=w>>1: wave=q&3, lane=(q>>2)*2+(w&1);
//          40 lanes/wave, oy-pairs adjacent in-lane for the pool shuffle.
// ---------------------------------------------------------------------------
__global__ __launch_bounds__(256, 2) void lenet_kernel(
    const float* __restrict__ img,     // (1024,3,32,32)
    const float* __restrict__ train,   // (50000,3,32,32)
    const int* __restrict__ refs,      // (1024,8)
    const float* __restrict__ w1, const float* __restrict__ b1,  // (6,3,5,5),(6)
    const float* __restrict__ w2, const float* __restrict__ b2)  // (16,6,5,5),(16)
{
    __shared__ __align__(16) float s_in[3 * 32 * 32];   // 12 KB, swizzled
    __shared__ __align__(16) float s_p1[6 * 14 * 32];   // 10.5 KB, swizzled

    const int blk = blockIdx.x;
    const int tid = threadIdx.x;
    const int lane = tid & 63;
    const int wv   = tid >> 6;

    const float* src = (blk < 1024)
        ? (img + (size_t)blk * 3072)
        : (train + (size_t)refs[blk - 1024] * 3072);
    const float4* src4 = (const float4*)src;

    // stage image, 3 float4 per thread, swizzled store (each f4 = one 16B slot)
    #pragma unroll
    for (int j = 0; j < 3; ++j) {
        const int i4 = tid + j * 256;            // 0..767
        const float4 v = src4[i4];
        const int ic   = i4 >> 8;
        const int row  = (i4 >> 3) & 31;
        const int slot = i4 & 7;
        *(float4*)(s_in + ic * 1024 + row * 32 + ((slot ^ (row & 7)) << 2)) = v;
    }
    __syncthreads();

    // ---- conv1 + relu + pool1 (fused). 196 items = (pos 0..97) x (och 0..1)
    // wave w: och = w>>1 (wave-uniform), pos = lane*2 + (w&1), lanes 0..48
    if (lane < 49) {
        const int och = wv >> 1;
        const int pos = lane * 2 + (wv & 1);     // 0..97
        const int py  = pos / 7;
        const int xt  = pos - py * 7;            // 4-col tile; ox4 = 4*xt
        const int r0  = py * 2;

        float acc[3][2][4];
        #pragma unroll
        for (int o = 0; o < 3; ++o) {
            const float b = b1[och * 3 + o];     // wave-uniform -> scalar
            #pragma unroll
            for (int r = 0; r < 2; ++r)
                #pragma unroll
                for (int j = 0; j < 4; ++j) acc[o][r][j] = b;
        }

        #pragma unroll 1
        for (int ic = 0; ic < 3; ++ic) {
            const float* base = s_in + ic * 1024;
            const float* wic  = w1 + och * 3 * 75 + ic * 25;  // uniform base
            float A[8], B[8];
            {
                const int row = r0, r7 = row & 7;
                const float4 lo = *(const float4*)(base + row * 32 + ((xt ^ r7) << 2));
                const float4 hi = *(const float4*)(base + row * 32 + (((xt + 1) ^ r7) << 2));
                A[0]=lo.x; A[1]=lo.y; A[2]=lo.z; A[3]=lo.w;
                A[4]=hi.x; A[5]=hi.y; A[6]=hi.z; A[7]=hi.w;
            }
            #pragma unroll
            for (int ky = 0; ky < 5; ++ky) {
                const int row = r0 + ky + 1, r7 = row & 7;
                const float4 lo = *(const float4*)(base + row * 32 + ((xt ^ r7) << 2));
                const float4 hi = *(const float4*)(base + row * 32 + (((xt + 1) ^ r7) << 2));
                B[0]=lo.x; B[1]=lo.y; B[2]=lo.z; B[3]=lo.w;
                B[4]=hi.x; B[5]=hi.y; B[6]=hi.z; B[7]=hi.w;
                #pragma unroll
                for (int o = 0; o < 3; ++o) {
                    #pragma unroll
                    for (int kx = 0; kx < 5; ++kx) {
                        const float w = wic[o * 75 + ky * 5 + kx];  // uniform -> s_load
                        #pragma unroll
                        for (int j = 0; j < 4; ++j) {
                            acc[o][0][j] = fmaf(A[j + kx], w, acc[o][0][j]);
                            acc[o][1][j] = fmaf(B[j + kx], w, acc[o][1][j]);
                        }
                    }
                }
                #pragma unroll
                for (int q = 0; q < 8; ++q) A[q] = B[q];  // row reuse across ky
            }
        }

        // 2x2 pool + relu -> s_p1[oc][py][2*xt .. 2*xt+1] (swizzled, float2)
        const int r7 = py & 7;
        const int px0 = xt * 2;   // even -> pair stays inside one 16B slot
        #pragma unroll
        for (int o = 0; o < 3; ++o) {
            const int oc = och * 3 + o;
            const float m0 = fmaxf(fmaxf(acc[o][0][0], acc[o][0][1]),
                                   fmaxf(acc[o][1][0], acc[o][1][1]));
            const float m1 = fmaxf(fmaxf(acc[o][0][2], acc[o][0][3]),
                                   fmaxf(acc[o][1][2], acc[o][1][3]));
            float* d = s_p1 + oc * 448 + py * 32 + (((px0 >> 2) ^ r7) << 2) + (px0 & 3);
            *(float2*)d = make_float2(fmaxf(m0, 0.0f), fmaxf(m1, 0.0f));
        }
    }
    __syncthreads();

    // ---- conv2 + relu + pool2 (fused). 160 items spread over 4 waves.
    if (lane < 40) {
        const int q  = (lane >> 1) * 4 + wv;     // 0..79 (oy-pair index)
        const int w  = q * 2 + (lane & 1);       // 0..159
        const int oc = w / 10;
        const int oy = w - oc * 10;

        float acc[10];
        {
            const float b = b2[oc];
            #pragma unroll
            for (int j = 0; j < 10; ++j) acc[j] = b;
        }
        const float* wrow = w2 + oc * 150;
        #pragma unroll 1
        for (int ic = 0; ic < 6; ++ic) {
            const float* base = s_p1 + ic * 448;
            const float* wic  = wrow + ic * 25;
            #pragma unroll
            for (int ky = 0; ky < 5; ++ky) {
                const int row = oy + ky, r7 = row & 7;
                const float* rb = base + row * 32;
                float in[14];
                const float4 q0 = *(const float4*)(rb + ((0 ^ r7) << 2));
                const float4 q1 = *(const float4*)(rb + ((1 ^ r7) << 2));
                const float4 q2 = *(const float4*)(rb + ((2 ^ r7) << 2));
                const float2 q3 = *(const float2*)(rb + ((3 ^ r7) << 2));
                in[0]=q0.x;  in[1]=q0.y;  in[2]=q0.z;  in[3]=q0.w;
                in[4]=q1.x;  in[5]=q1.y;  in[6]=q1.z;  in[7]=q1.w;
                in[8]=q2.x;  in[9]=q2.y;  in[10]=q2.z; in[11]=q2.w;
                in[12]=q3.x; in[13]=q3.y;
                #pragma unroll
                for (int kx = 0; kx < 5; ++kx) {
                    const float wgt = wic[ky * 5 + kx];   // per-lane, L1-hot
                    #pragma unroll
                    for (int j = 0; j < 10; ++j)
                        acc[j] = fmaf(in[j + kx], wgt, acc[j]);
                }
            }
        }
        // horizontal pool in-lane, vertical via adjacent lane (same q -> same wave)
        float v[5];
        #pragma unroll
        for (int k = 0; k < 5; ++k) v[k] = fmaxf(acc[2 * k], acc[2 * k + 1]);
        float* fo = g_feat + (size_t)blk * 400 + oc * 25 + (oy >> 1) * 5;
        #pragma unroll
        for (int k = 0; k < 5; ++k) {
            const float m = fmaxf(v[k], __shfl_down(v[k], 1));
            if ((lane & 1) == 0) fo[k] = fmaxf(m, 0.0f);   // oy even
        }
    }
}

// ---------------------------------------------------------------------------
// Kernel 2: head. 256 blocks x 512 threads, FOUR n per block.
// Weight traffic amortized 4x (383MB -> 54MB) and ordered weight-row-major:
// all 32 groups advance through the same weight rows together -> L1 hits.
// Dots enumerated d in [0,912): d<432: (Wf row h=d/36) x (vec d%36);
// else: (Wg row rg=(d-432)>>2) x (img feat of n_l=(d-432)&3).
// ---------------------------------------------------------------------------
__global__ __launch_bounds__(512) void head_kernel(
    const float* __restrict__ mem,   // (50000,10)
    const float* __restrict__ Wf, const float* __restrict__ bf,   // (12,400),(12)
    const float* __restrict__ Wg, const float* __restrict__ bg,   // (120,400),(120)
    const float* __restrict__ Wm, const float* __restrict__ bm,   // (10,10),(10)
    const int* __restrict__ refs,    // (1024,8)
    float* __restrict__ out)         // (1024,10)
{
    const int blk = blockIdx.x;      // 256
    const int tid = threadIdx.x;     // 512
    const int n0  = blk * 4;

    __shared__ __align__(16) float s_f[36 * 400];   // 57.6 KB: 4n x (img + 8 refs)
    __shared__ float s_out[4 * 228];   // per n: [0,12)=x, [12,108)=rx(s*12+h), [108,228)=grad(h*10+c)
    __shared__ float s_diff[4 * 96];
    __shared__ float s_dist[4 * 8];
    __shared__ float s_logits[4 * 80];

    // stage 36 feature rows (coalesced f4)
    for (int i = tid; i < 3600; i += 512) {
        const int r = i / 100, c = i - r * 100;
        const int n_l = r / 9, v = r - n_l * 9;
        const float* srcp = (v == 0)
            ? (g_feat + (size_t)(n0 + n_l) * 400)
            : (g_feat + (size_t)(1024 + (n0 + n_l) * 8 + (v - 1)) * 400);
        *(float4*)(s_f + r * 400 + c * 4) = *(const float4*)(srcp + c * 4);
    }
    __syncthreads();

    // Phase A: 912 dots of length 400, 32 groups of 16 lanes, 29 rounds
    const int grp = tid >> 4;
    const int l16 = tid & 15;
    for (int t = 0; t < 29; ++t) {
        const int d = t * 32 + grp;
        if (d < 912) {
            const float* w;
            const float* f;
            if (d < 432) {
                const int h = d / 36, vec = d - h * 36;
                w = Wf + h * 400;  f = s_f + vec * 400;
            } else {
                const int e = d - 432;
                const int rg = e >> 2, n_l = e & 3;
                w = Wg + rg * 400; f = s_f + n_l * 9 * 400;
            }
            float a = 0.0f;
            #pragma unroll
            for (int it = 0; it < 7; ++it) {
                const int k = it * 64 + l16 * 4;
                if (k < 400) {
                    const float4 wvv = *(const float4*)(w + k);
                    const float4 fv  = *(const float4*)(f + k);
                    a = fmaf(wvv.x, fv.x, a); a = fmaf(wvv.y, fv.y, a);
                    a = fmaf(wvv.z, fv.z, a); a = fmaf(wvv.w, fv.w, a);
                }
            }
            #pragma unroll
            for (int m = 8; m; m >>= 1) a += __shfl_xor(a, m);
            if (l16 == 0) {
                if (d < 432) {
                    const int h = d / 36, vec = d - h * 36;
                    const int n_l = vec / 9, v = vec - n_l * 9;
                    s_out[n_l * 228 + (v == 0 ? h : 12 + (v - 1) * 12 + h)] = a + bf[h];
                } else {
                    const int e = d - 432;
                    const int rg = e >> 2, n_l = e & 3;
                    s_out[n_l * 228 + 108 + rg] = a + bg[rg];
                }
            }
        }
    }
    __syncthreads();

    // diff[n_l][s*12+h] = x[h] - rx[s*12+h]
    if (tid < 384) {
        const int n_l = tid / 96, i = tid - n_l * 96;
        const int h = i % 12;
        s_diff[tid] = s_out[n_l * 228 + h] - s_out[n_l * 228 + 12 + i];
    }
    __syncthreads();

    // norms + softmax (wave 0, lockstep)
    if (tid < 32) {
        const int n_l = tid >> 3, s = tid & 7;
        float nn = 0.0f;
        #pragma unroll
        for (int h = 0; h < 12; ++h) {
            const float dd = s_diff[n_l * 96 + s * 12 + h];
            nn = fmaf(dd, dd, nn);
        }
        s_dist[tid] = -sqrtf(nn);
    }
    if (tid < 4) {
        float mx = s_dist[tid * 8];
        #pragma unroll
        for (int s = 1; s < 8; ++s) mx = fmaxf(mx, s_dist[tid * 8 + s]);
        float e[8]; float tot = 0.0f;
        #pragma unroll
        for (int s = 0; s < 8; ++s) { e[s] = expf(s_dist[tid * 8 + s] - mx); tot += e[s]; }
        #pragma unroll
        for (int s = 0; s < 8; ++s) s_dist[tid * 8 + s] = e[s] / tot;
    }

    // logits[n_l][s,c] = mem[refs].Wm[c] + bm[c] + sum_h diff*grad  (indep of dist)
    if (tid < 320) {
        const int n_l = tid / 80, r = tid - n_l * 80;
        const int s = r / 10, c = r - s * 10;
        const float* mrow = mem + (size_t)refs[(n0 + n_l) * 8 + s] * 10;
        float a = bm[c];
        #pragma unroll
        for (int k = 0; k < 10; ++k) a = fmaf(mrow[k], Wm[c * 10 + k], a);
        #pragma unroll
        for (int h = 0; h < 12; ++h)
            a = fmaf(s_diff[n_l * 96 + s * 12 + h], s_out[n_l * 228 + 108 + h * 10 + c], a);
        s_logits[n_l * 80 + r] = a;
    }
    __syncthreads();

    if (tid < 40) {
        const int n_l = tid / 10, c = tid - n_l * 10;
        float a = 0.0f;
        #pragma unroll
        for (int s = 0; s < 8; ++s)
            a = fmaf(s_dist[n_l * 8 + s], s_logits[n_l * 80 + s * 10 + c], a);
        out[(n0 + n_l) * 10 + c] = a;
    }
}

extern "C" void kernel_launch(void* const* d_in, const int* in_sizes, int n_in,
                              void* d_out, int out_size, void* d_ws, size_t ws_size,
                              hipStream_t stream) {
    const float* img   = (const float*)d_in[0];
    const float* train = (const float*)d_in[1];
    const float* mem   = (const float*)d_in[2];
    const float* w1    = (const float*)d_in[3];
    const float* b1    = (const float*)d_in[4];
    const float* w2    = (const float*)d_in[5];
    const float* b2    = (const float*)d_in[6];
    const float* Wf    = (const float*)d_in[7];
    const float* bf    = (const float*)d_in[8];
    const float* Wg    = (const float*)d_in[9];
    const float* bg    = (const float*)d_in[10];
    const float* Wm    = (const float*)d_in[11];
    const float* bm    = (const float*)d_in[12];
    // d_in[13] = idx (unused by the reference)
    const int*   refs  = (const int*)d_in[14];
    float* out = (float*)d_out;

    lenet_kernel<<<9216, 256, 0, stream>>>(img, train, refs, w1, b1, w2, b2);
    head_kernel<<<256, 512, 0, stream>>>(mem, Wf, bf, Wg, bg, Wm, bm, refs, out);
}